// Round 17
// baseline (200.378 us; speedup 1.0000x reference)
//
#include <hip/hip_runtime.h>
#include <hip/hip_bf16.h>
#include <math.h>

#define B_ 512
#define N_ 32
#define D_ 300
#define R_ 6
#define E_ 256
#define NG_ 50000
#define NS_ 25000

#define KTOT 2100      // 6*300 (Wrel) + 300 (W0)
#define YLD  2112      // Y bf16 leading dim (33*64)
#define XLD  320       // X0H bf16 leading dim (5*64)
#define PLD  304       // k1b partial leading dim (fp32)
#define NCBG 782       // ceil(50000/64)
#define NCBS 391       // ceil(25000/64)
#define CPADG (NCBG*64)   // 50048
#define CPADS (NCBS*64)   // 25024
#define NTILE (NCBG+NCBS) // 1173
#define GRP12 147         // col-tile groups; 8 tiles/block; grid = 4*147 = 588

typedef __attribute__((ext_vector_type(8))) short short8;
typedef __attribute__((ext_vector_type(4))) float f32x4;

__device__ __forceinline__ unsigned short f2bf(float f) {
  __hip_bfloat16 h = __float2bfloat16(f);
  return *reinterpret_cast<unsigned short*>(&h);
}

__device__ __forceinline__ void gload_lds16(const unsigned short* g, unsigned short* l) {
  __builtin_amdgcn_global_load_lds(
      (const __attribute__((address_space(1))) void*)g,
      (__attribute__((address_space(3))) void*)l,
      16, 0, 0);
}

// ---------------- K1a: collapse graph to Y[b, 2112] bf16 (zero k-pad) ----------------
// grid (512, 2): half h handles relations r in [3h, 3h+3); h==0 also writes W0 row + pad.
__global__ __launch_bounds__(256) void k1a_coef_y(
    const float* __restrict__ x, const int* __restrict__ ei,
    const int* __restrict__ et, unsigned short* __restrict__ Y)
{
  int b = blockIdx.x;
  int half = blockIdx.y;
  int tid = threadIdx.x;
  __shared__ int srcs[E_], dsts[E_], ets[E_];
  __shared__ int degc[R_*N_];
  __shared__ float coef[R_*N_];

  srcs[tid] = ei[b*2*E_ + tid];
  dsts[tid] = ei[b*2*E_ + E_ + tid];
  ets[tid]  = et[b*E_ + tid];
  if (tid < R_*N_) { degc[tid] = 0; coef[tid] = 0.0f; }
  __syncthreads();

  atomicAdd(&degc[ets[tid]*N_ + dsts[tid]], 1);
  __syncthreads();

  if (dsts[tid] == 0) {
    int r = ets[tid];
    float ds = 1.0f + (float)degc[r*N_ + srcs[tid]];
    float dd = 1.0f + (float)degc[r*N_ + 0];
    atomicAdd(&coef[r*N_ + srcs[tid]], rsqrtf(ds*dd));
  }
  if (tid < R_) {
    atomicAdd(&coef[tid*N_ + 0], 1.0f/(1.0f + (float)degc[tid*N_]));
  }
  __syncthreads();

  const float* xb = x + (size_t)b*N_*D_;
  unsigned short* Yb = Y + (size_t)b*YLD;
  for (int k = tid; k < D_; k += 256) {
    #pragma unroll
    for (int rr = 0; rr < 3; ++rr) {
      int r = half*3 + rr;
      float acc = 0.0f;
      for (int n = 0; n < N_; ++n) {
        float c = coef[r*N_ + n];          // uniform across threads
        if (c != 0.0f) acc += c * xb[n*D_ + k];
      }
      Yb[r*D_ + k] = f2bf(acc);
    }
    if (half == 0) Yb[6*D_ + k] = f2bf(xb[k]);   // x[b,0,:] for the W0 term
  }
  if (half == 0 && tid < YLD - KTOT) Yb[KTOT + tid] = 0;
}

// ---------------- wtrans3: wide-chunk W transpose, G+S fused, low VGPR ----------------
__global__ __launch_bounds__(256) void wtrans3(
    const float* __restrict__ Wg, unsigned short* __restrict__ Wttg,
    const float* __restrict__ Wsrc, unsigned short* __restrict__ Wtts)
{
  __shared__ unsigned short smem[64*264];
  const int bid = blockIdx.x;
  const int tid = threadIdx.x;

  const float* W; unsigned short* Wtt; int C, Cpad, cb, kb;
  if (bid < 980) { W = Wg;   Wtt = Wttg; C = NG_; Cpad = CPADG; cb = bid % 196; kb = bid / 196; }
  else { int ix = bid - 980; W = Wsrc; Wtt = Wtts; C = NS_; Cpad = CPADS; cb = ix % 98; kb = ix / 98; }
  const int c0 = min(cb*256, C - 256);
  const int k0 = kb * 64;

  const int rw = tid >> 6;
  const int cq = (tid & 63) * 4;
  #pragma unroll
  for (int it = 0; it < 16; ++it) {
    int kl = it*4 + rw;
    int k = k0 + kl;
    float4 v = make_float4(0.f, 0.f, 0.f, 0.f);
    if (k < D_) v = *reinterpret_cast<const float4*>(&W[(size_t)k*C + c0 + cq]);
    ushort4 u;
    u.x = f2bf(v.x); u.y = f2bf(v.y); u.z = f2bf(v.z); u.w = f2bf(v.w);
    *reinterpret_cast<ushort4*>(&smem[kl*264 + cq]) = u;
  }
  __syncthreads();

  const int c_l = tid;
  #pragma unroll
  for (int o = 0; o < 8; ++o) {
    unsigned short u[8];
    #pragma unroll
    for (int j = 0; j < 8; ++j) u[j] = smem[(o*8 + j)*264 + c_l];
    size_t goct = (size_t)(k0 >> 3) + o;
    *reinterpret_cast<short8*>(&Wtt[(goct*Cpad + c0 + c_l) * 8]) =
        *reinterpret_cast<const short8*>(u);
  }
}

// ---------------- k1b gemm (round-5 proven): BM=256, BN=64, BK=64 ----------------
__global__ __launch_bounds__(256, 3) void gemm_k1b(
    const unsigned short* __restrict__ A, int lda,
    const float* __restrict__ B0, const float* __restrict__ B1,
    float* __restrict__ P1, int nz)
{
  __shared__ unsigned short As[256*64];
  __shared__ unsigned short Bs[64*80];

  const int tid  = threadIdx.x;
  const int lane = tid & 63, wid = tid >> 6;
  const int lr = lane & 15, lg = lane >> 4;

  int id = blockIdx.x;          // 2 mb * 5 cb * nz
  int mb = id & 1; id >>= 1;
  int cb = id % 5, z = id / 5;
  const int m0 = mb*256, c0 = cb*64;
  const int ksplit = 6*D_;

  const int r8 = lane >> 3, sl = lane & 7;
  const int c_l = tid & 63, ob = tid >> 6;
  const int gcol = c0 + c_l;
  const bool cok = (gcol < D_);

  f32x4 acc[4][4];
  #pragma unroll
  for (int a = 0; a < 4; ++a)
    #pragma unroll
    for (int b = 0; b < 4; ++b) acc[a][b] = (f32x4){0.f,0.f,0.f,0.f};

  for (int t = z; t < 33; t += nz) {
    const int kt = t * 64;
    __syncthreads();

    #pragma unroll
    for (int i = 0; i < 8; ++i) {
      int row_l = wid*64 + i*8 + r8;
      int sslot = sl ^ (row_l & 7);
      gload_lds16(A + (size_t)(m0 + row_l)*lda + kt + sslot*8, &As[(wid*64 + i*8)*64]);
    }

    #pragma unroll
    for (int it = 0; it < 2; ++it) {
      int o  = ob + it*4;
      int kb = kt + o*8;
      unsigned short u[8];
      #pragma unroll
      for (int j = 0; j < 8; ++j) {
        int k = kb + j;
        float v = 0.f;
        if (cok && k < KTOT)
          v = (k < ksplit) ? B0[(size_t)k*D_ + gcol]
                           : B1[(size_t)(k - ksplit)*D_ + gcol];
        u[j] = f2bf(v);
      }
      *reinterpret_cast<short8*>(&Bs[c_l*80 + ((o ^ (c_l & 7)) << 3)]) =
          *reinterpret_cast<const short8*>(u);
    }

    __syncthreads();

    #pragma unroll
    for (int kk = 0; kk < 2; ++kk) {
      const int q = kk*4 + lg;
      short8 bfr[4];
      #pragma unroll
      for (int b = 0; b < 4; ++b) {
        int col = b*16 + lr;
        bfr[b] = *reinterpret_cast<const short8*>(&Bs[col*80 + ((q ^ (col & 7)) << 3)]);
      }
      #pragma unroll
      for (int a = 0; a < 4; ++a) {
        int row = wid*64 + a*16 + lr;
        short8 af = *reinterpret_cast<const short8*>(&As[row*64 + ((q ^ (row & 7)) << 3)]);
        #pragma unroll
        for (int b = 0; b < 4; ++b)
          acc[a][b] = __builtin_amdgcn_mfma_f32_16x16x32_bf16(af, bfr[b], acc[a][b], 0, 0, 0);
      }
    }
  }

  float* o = P1 + (size_t)z * (size_t)B_ * PLD;
  #pragma unroll
  for (int a = 0; a < 4; ++a) {
    int row = m0 + wid*64 + a*16 + lg*4;
    #pragma unroll
    for (int b = 0; b < 4; ++b) {
      int col = c0 + b*16 + lr;
      if (col < D_) {
        #pragma unroll
        for (int i = 0; i < 4; ++i)
          o[(size_t)(row + i)*PLD + col] = acc[a][b][i];
      }
    }
  }
}

// ---------------- K1c: reduce z-partials, leaky, emit bf16 X0H [512][320] ----------------
__global__ __launch_bounds__(256) void k1c_reduce(
    const float* __restrict__ part, int nz, unsigned short* __restrict__ X0Hbf)
{
  int idx = blockIdx.x*256 + threadIdx.x;
  if (idx >= B_*XLD) return;
  int m = idx / XLD, c = idx % XLD;
  float v = 0.f;
  if (c < D_) {
    for (int zz = 0; zz < nz; ++zz) v += part[(size_t)zz*B_*PLD + (size_t)m*PLD + c];
    v = (v >= 0.f) ? v : 0.1f*v;
  }
  X0Hbf[idx] = f2bf(v);
}

// ---------------- gemm12: heads, two-pass recompute; 8 tiles/block ----------------
// BM=128 per block (mb=0..3); grid = 4*GRP12 = 588 (single resident block-wave at
// 3 blocks/CU), bijective XCD swizzle (q=73, r=4). A-fragments loaded ONCE per block;
// per tile: 10 DMA + 5 counted-vmcnt stages + clamped-window epilogue.
// MODE 0: per-row (max,sumexp) -> part (epilogue vmem = 12).
// MODE 1: out = acc + bias - lse[row] via per-wave LDS staging, 256B-contiguous
//         stores (epilogue vmem = 44).
template<int MODE>
__global__ __launch_bounds__(256, 3) void gemm12(
    const unsigned short* __restrict__ X0H,
    const unsigned short* __restrict__ Wttg, const unsigned short* __restrict__ Wtts,
    const float* __restrict__ bg, const float* __restrict__ bs,
    float* __restrict__ out, float2* __restrict__ Pg, float2* __restrict__ Ps,
    const float* __restrict__ lse)
{
  __shared__ unsigned short Bs[5][4096];   // 5 stages x 8 KB
  __shared__ float eplds[2080];            // 4 waves x [8][65] fp32 (8.3 KB)

  // bijective XCD-chunked swizzle for grid 588 = 8*73 + 4
  int bid = blockIdx.x;
  {
    int q = 73, r = 4, xcd = bid & 7, loc = bid >> 3;
    bid = (xcd < r ? xcd*(q+1) : r*(q+1) + (xcd-r)*q) + loc;
  }
  const int mb = bid & 3;
  const int g  = bid >> 2;                 // 0..146
  const int m0 = mb * 128;

  const int tid = threadIdx.x;
  const int lane = tid & 63, w = tid >> 6;
  const int lr = lane & 15, lg = lane >> 4;

  // ---- A fragments, once per block ----
  short8 af[2][10];
  #pragma unroll
  for (int a = 0; a < 2; ++a) {
    const unsigned short* Ar = X0H + (size_t)(m0 + w*32 + a*16 + lr)*XLD + lg*8;
    #pragma unroll
    for (int ks = 0; ks < 10; ++ks)
      af[a][ks] = *reinterpret_cast<const short8*>(Ar + ks*32);
  }
  __builtin_amdgcn_sched_barrier(0);

  auto dma_tile = [&](int tt) {
    const bool hg = (tt < NCBG);
    const unsigned short* Wtt = hg ? Wttg : Wtts;
    const size_t cp = hg ? CPADG : CPADS;
    const int C = hg ? NG_ : NS_;
    const int cb = hg ? tt : tt - NCBG;
    const int c0c = min(cb*64, C - 64);
    #pragma unroll
    for (int j = 0; j < 5; ++j) {
      #pragma unroll
      for (int i2 = 0; i2 < 2; ++i2) {
        int o = w*2 + i2;
        gload_lds16(Wtt + ((size_t)(j*8 + o)*cp + (size_t)c0c + lane)*8, &Bs[j][o*512]);
      }
    }
  };

  dma_tile(g);
  __builtin_amdgcn_sched_barrier(0);

  f32x4 acc[2][4];

#define MF12(j) do {                                                           \
    _Pragma("unroll")                                                          \
    for (int kk = 0; kk < 2; ++kk) {                                           \
      short8 bfr[4];                                                           \
      _Pragma("unroll")                                                        \
      for (int b = 0; b < 4; ++b)                                              \
        bfr[b] = *reinterpret_cast<const short8*>(                             \
            &Bs[j][(kk*4 + lg)*512 + (b*16 + lr)*8]);                          \
      _Pragma("unroll")                                                        \
      for (int a = 0; a < 2; ++a)                                              \
        _Pragma("unroll")                                                      \
        for (int b = 0; b < 4; ++b)                                            \
          acc[a][b] = __builtin_amdgcn_mfma_f32_16x16x32_bf16(                 \
              af[a][(j)*2 + kk], bfr[b], acc[a][b], 0, 0, 0);                  \
    }                                                                          \
  } while (0)

#define ST12(j, NSTR) do {                                                     \
    asm volatile("s_waitcnt vmcnt(" NSTR ")" ::: "memory");                    \
    __builtin_amdgcn_s_barrier();                                              \
    __builtin_amdgcn_sched_barrier(0);                                         \
    MF12(j);                                                                   \
  } while (0)

  for (int tl = 0; tl < 8; ++tl) {
    const int tt = g + tl*GRP12;
    if (tt >= NTILE) break;

    #pragma unroll
    for (int a = 0; a < 2; ++a)
      #pragma unroll
      for (int b = 0; b < 4; ++b) acc[a][b] = (f32x4){0.f,0.f,0.f,0.f};

    if (tl == 0) {
      ST12(0, "8"); ST12(1, "6"); ST12(2, "4"); ST12(3, "2"); ST12(4, "0");
    } else if (MODE == 0) {
      // queue: [D_cur:10][E_prev:12];  count = 12 + 8 - 2j
      ST12(0, "20"); ST12(1, "18"); ST12(2, "16"); ST12(3, "14"); ST12(4, "12");
    } else {
      // queue: [D_cur:10][E_prev:44];  count = 44 + 8 - 2j
      ST12(0, "52"); ST12(1, "50"); ST12(2, "48"); ST12(3, "46"); ST12(4, "44");
    }

    // Bs free after all waves' stage-4 ds_reads complete
    asm volatile("s_waitcnt lgkmcnt(0)" ::: "memory");
    __builtin_amdgcn_s_barrier();
    __builtin_amdgcn_sched_barrier(0);

    const int tn = tt + GRP12;
    if (tl < 7 && tn < NTILE) dma_tile(tn);
    __builtin_amdgcn_sched_barrier(0);

    // ---- epilogue (clamped window; stable op counts) ----
    {
      const bool hg = (tt < NCBG);
      const int C = hg ? NG_ : NS_;
      const int cb = hg ? tt : tt - NCBG;
      const int c0o = cb*64;
      const int c0c = min(c0o, C - 64);
      const float* bia = hg ? bg : bs;

      float bv[4];
      #pragma unroll
      for (int b = 0; b < 4; ++b) bv[b] = bia[c0c + b*16 + lr];   // 4 loads

      if constexpr (MODE == 0) {
        float2* part = hg ? Pg : Ps;
        #pragma unroll
        for (int a = 0; a < 2; ++a) {
          #pragma unroll
          for (int i = 0; i < 4; ++i) {
            int row = m0 + w*32 + a*16 + lg*4 + i;
            float v[4], mx = -3.0e38f;
            #pragma unroll
            for (int b = 0; b < 4; ++b) {
              v[b] = acc[a][b][i] + bv[b];
              if (c0c + b*16 + lr < c0o) v[b] = -3.0e38f;   // mask duplicate cols
              mx = fmaxf(mx, v[b]);
            }
            #pragma unroll
            for (int off = 1; off < 16; off <<= 1) mx = fmaxf(mx, __shfl_xor(mx, off));
            float s = 0.f;
            #pragma unroll
            for (int b = 0; b < 4; ++b) s += __expf(v[b] - mx);
            #pragma unroll
            for (int off = 1; off < 16; off <<= 1) s += __shfl_xor(s, off);
            if (lr == 0) part[(size_t)cb*512 + row] = make_float2(mx, s);  // 8 stores
          }
        }
      } else {
        float* outp = hg ? out : out + (size_t)B_*NG_;
        const float* lp = lse + (hg ? 0 : 512);
        float* ep = &eplds[w * 520];          // per-wave [8][65]
        #pragma unroll
        for (int a = 0; a < 2; ++a) {
          #pragma unroll
          for (int ip = 0; ip < 2; ++ip) {
            // WAR fence: previous round's reads done before overwriting (wave-local)
            asm volatile("s_waitcnt lgkmcnt(0)" ::: "memory");
            __builtin_amdgcn_sched_barrier(0);
            #pragma unroll
            for (int d = 0; d < 2; ++d) {
              int grow = m0 + w*32 + a*16 + lg*4 + 2*ip + d;
              float L = lp[grow];                                  // 8 lse loads total
              #pragma unroll
              for (int b = 0; b < 4; ++b)
                ep[(2*lg + d)*65 + b*16 + lr] = acc[a][b][2*ip + d] + bv[b] - L;
            }
            asm volatile("s_waitcnt lgkmcnt(0)" ::: "memory");
            __builtin_amdgcn_sched_barrier(0);
            #pragma unroll
            for (int rloc = 0; rloc < 8; ++rloc) {
              float v = ep[rloc*65 + lane];
              int grow = m0 + w*32 + a*16 + 4*(rloc >> 1) + 2*ip + (rloc & 1);
              outp[(size_t)grow*C + c0c + lane] = v;               // 32 stores total
            }
          }
        }
      }
    }
    __builtin_amdgcn_sched_barrier(0);
  }
#undef MF12
#undef ST12
}

// ---------------- k5b: combine tile-major (m,s) partials -> lse[1024] ----------------
__global__ __launch_bounds__(256) void k5b(
    const float2* __restrict__ Pg, const float2* __restrict__ Ps,
    float* __restrict__ lse)
{
  const int blk = blockIdx.x;            // 0..127
  const bool hg = (blk < 64);
  const float2* p = hg ? Pg : Ps;
  const int n = hg ? NCBG : NCBS;
  const int r0 = (hg ? blk : blk - 64) * 8;
  const int tid = threadIdx.x;
  const int rr = tid & 7;
  const int row = r0 + rr;

  float m = -3.0e38f, s = 0.f;
  for (int t = tid >> 3; t < n; t += 32) {
    float2 v = p[(size_t)t*512 + row];
    float mn = fmaxf(m, v.x);
    s = s*__expf(m - mn) + v.y*__expf(v.x - mn);
    m = mn;
  }
  #pragma unroll
  for (int off = 8; off < 64; off <<= 1) {
    float m2 = __shfl_xor(m, off), s2 = __shfl_xor(s, off);
    float mn = fmaxf(m, m2);
    s = s*__expf(m - mn) + s2*__expf(m2 - mn);
    m = mn;
  }
  __shared__ float ms[4][8], ss[4][8];
  const int wv = tid >> 6;
  if ((tid & 63) < 8) { ms[wv][tid & 7] = m; ss[wv][tid & 7] = s; }
  __syncthreads();
  if (tid < 8) {
    float M = ms[0][tid], S = ss[0][tid];
    #pragma unroll
    for (int ww = 1; ww < 4; ++ww) {
      float mn = fmaxf(M, ms[ww][tid]);
      S = S*__expf(M - mn) + ss[ww][tid]*__expf(ms[ww][tid] - mn);
      M = mn;
    }
    lse[(hg ? 0 : 512) + r0 + tid] = M + __logf(S);
  }
}

// =====================================================================
extern "C" void kernel_launch(void* const* d_in, const int* in_sizes, int n_in,
                              void* d_out, int out_size, void* d_ws, size_t ws_size,
                              hipStream_t stream)
{
  const float* x    = (const float*)d_in[0];
  const int*   ei   = (const int*)  d_in[1];
  const int*   et   = (const int*)  d_in[2];
  const float* Wrel = (const float*)d_in[3];
  const float* W0   = (const float*)d_in[4];
  const float* Wg   = (const float*)d_in[5];
  const float* bg   = (const float*)d_in[6];
  const float* Ws   = (const float*)d_in[7];
  const float* bs   = (const float*)d_in[8];
  float* out = (float*)d_out;

  // ws layout (bytes): Ybf | X0H | P1 | Pg | Ps | LSE | Wttg | Wtts (~60.3 MB)
  char* p = (char*)d_ws;
  unsigned short* Ybf = (unsigned short*)p;  p += (size_t)B_*YLD*2;
  unsigned short* X0H = (unsigned short*)p;  p += (size_t)B_*XLD*2;
  float*  P1  = (float*)p;                   p += (size_t)8*B_*PLD*4;
  float2* Pg  = (float2*)p;                  p += (size_t)NCBG*512*8;
  float2* Ps  = (float2*)p;                  p += (size_t)NCBS*512*8;
  float*  LSE = (float*)p;                   p += 4096;
  unsigned short* Wttg = (unsigned short*)p; p += (size_t)40*CPADG*16;
  unsigned short* Wtts = (unsigned short*)p;

  // W pre-transpose, both heads, wide-chunk reads (low VGPR, one launch)
  wtrans3<<<980 + 490, 256, 0, stream>>>(Wg, Wttg, Ws, Wtts);

  k1a_coef_y<<<dim3(B_, 2), 256, 0, stream>>>(x, ei, et, Ybf);

  // k1b: P1[z] = Y @ [Wrel;W0] partials (z-split over 33 K-tiles)
  gemm_k1b<<<2*5*8, 256, 0, stream>>>(Ybf, YLD, Wrel, W0, P1, 8);
  k1c_reduce<<<(B_*XLD + 255)/256, 256, 0, stream>>>(P1, 8, X0H);

  // pass1: per-tile row stats -> Pg/Ps (no logits write)
  gemm12<0><<<4*GRP12, 256, 0, stream>>>(X0H, Wttg, Wtts, bg, bs,
                                         nullptr, Pg, Ps, nullptr);
  k5b<<<128, 256, 0, stream>>>(Pg, Ps, LSE);

  // pass2: recompute logits, write out = acc + bias - lse
  gemm12<1><<<4*GRP12, 256, 0, stream>>>(X0H, Wttg, Wtts, bg, bs,
                                         out, nullptr, nullptr, LSE);
}

// Round 19
// 197.368 us; speedup vs baseline: 1.0152x; 1.0152x over previous
//
#include <hip/hip_runtime.h>
#include <hip/hip_bf16.h>
#include <math.h>

#define B_ 512
#define N_ 32
#define D_ 300
#define R_ 6
#define E_ 256
#define NG_ 50000
#define NS_ 25000

#define KTOT 2100      // 6*300 (Wrel) + 300 (W0)
#define YLD  2112      // Y bf16 leading dim (33*64)
#define XLD  320       // X0H bf16 leading dim (5*64)
#define PLD  304       // k1b partial leading dim (fp32)
#define NCBG 782       // ceil(50000/64)
#define NCBS 391       // ceil(25000/64)
#define CPADG (NCBG*64)   // 50048
#define CPADS (NCBS*64)   // 25024
#define NTILE (NCBG+NCBS) // 1173
#define GRP12 294         // col-tile groups; 4 tiles/block; grid = 4*294 = 1176 = 8*147

typedef __attribute__((ext_vector_type(8))) short short8;
typedef __attribute__((ext_vector_type(4))) float f32x4;

__device__ __forceinline__ unsigned short f2bf(float f) {
  __hip_bfloat16 h = __float2bfloat16(f);
  return *reinterpret_cast<unsigned short*>(&h);
}

__device__ __forceinline__ void gload_lds16(const unsigned short* g, unsigned short* l) {
  __builtin_amdgcn_global_load_lds(
      (const __attribute__((address_space(1))) void*)g,
      (__attribute__((address_space(3))) void*)l,
      16, 0, 0);
}

// ---------------- K1a: collapse graph to Y[b, 2112] bf16 (zero k-pad) ----------------
// grid (512, 2): half h handles relations r in [3h, 3h+3); h==0 also writes W0 row + pad.
__global__ __launch_bounds__(256) void k1a_coef_y(
    const float* __restrict__ x, const int* __restrict__ ei,
    const int* __restrict__ et, unsigned short* __restrict__ Y)
{
  int b = blockIdx.x;
  int half = blockIdx.y;
  int tid = threadIdx.x;
  __shared__ int srcs[E_], dsts[E_], ets[E_];
  __shared__ int degc[R_*N_];
  __shared__ float coef[R_*N_];

  srcs[tid] = ei[b*2*E_ + tid];
  dsts[tid] = ei[b*2*E_ + E_ + tid];
  ets[tid]  = et[b*E_ + tid];
  if (tid < R_*N_) { degc[tid] = 0; coef[tid] = 0.0f; }
  __syncthreads();

  atomicAdd(&degc[ets[tid]*N_ + dsts[tid]], 1);
  __syncthreads();

  if (dsts[tid] == 0) {
    int r = ets[tid];
    float ds = 1.0f + (float)degc[r*N_ + srcs[tid]];
    float dd = 1.0f + (float)degc[r*N_ + 0];
    atomicAdd(&coef[r*N_ + srcs[tid]], rsqrtf(ds*dd));
  }
  if (tid < R_) {
    atomicAdd(&coef[tid*N_ + 0], 1.0f/(1.0f + (float)degc[tid*N_]));
  }
  __syncthreads();

  const float* xb = x + (size_t)b*N_*D_;
  unsigned short* Yb = Y + (size_t)b*YLD;
  for (int k = tid; k < D_; k += 256) {
    #pragma unroll
    for (int rr = 0; rr < 3; ++rr) {
      int r = half*3 + rr;
      float acc = 0.0f;
      for (int n = 0; n < N_; ++n) {
        float c = coef[r*N_ + n];          // uniform across threads
        if (c != 0.0f) acc += c * xb[n*D_ + k];
      }
      Yb[r*D_ + k] = f2bf(acc);
    }
    if (half == 0) Yb[6*D_ + k] = f2bf(xb[k]);   // x[b,0,:] for the W0 term
  }
  if (half == 0 && tid < YLD - KTOT) Yb[KTOT + tid] = 0;
}

// ---------------- wtrans3: wide-chunk W transpose, G+S fused, low VGPR ----------------
__global__ __launch_bounds__(256) void wtrans3(
    const float* __restrict__ Wg, unsigned short* __restrict__ Wttg,
    const float* __restrict__ Wsrc, unsigned short* __restrict__ Wtts)
{
  __shared__ unsigned short smem[64*264];
  const int bid = blockIdx.x;
  const int tid = threadIdx.x;

  const float* W; unsigned short* Wtt; int C, Cpad, cb, kb;
  if (bid < 980) { W = Wg;   Wtt = Wttg; C = NG_; Cpad = CPADG; cb = bid % 196; kb = bid / 196; }
  else { int ix = bid - 980; W = Wsrc; Wtt = Wtts; C = NS_; Cpad = CPADS; cb = ix % 98; kb = ix / 98; }
  const int c0 = min(cb*256, C - 256);
  const int k0 = kb * 64;

  const int rw = tid >> 6;
  const int cq = (tid & 63) * 4;
  #pragma unroll
  for (int it = 0; it < 16; ++it) {
    int kl = it*4 + rw;
    int k = k0 + kl;
    float4 v = make_float4(0.f, 0.f, 0.f, 0.f);
    if (k < D_) v = *reinterpret_cast<const float4*>(&W[(size_t)k*C + c0 + cq]);
    ushort4 u;
    u.x = f2bf(v.x); u.y = f2bf(v.y); u.z = f2bf(v.z); u.w = f2bf(v.w);
    *reinterpret_cast<ushort4*>(&smem[kl*264 + cq]) = u;
  }
  __syncthreads();

  const int c_l = tid;
  #pragma unroll
  for (int o = 0; o < 8; ++o) {
    unsigned short u[8];
    #pragma unroll
    for (int j = 0; j < 8; ++j) u[j] = smem[(o*8 + j)*264 + c_l];
    size_t goct = (size_t)(k0 >> 3) + o;
    *reinterpret_cast<short8*>(&Wtt[(goct*Cpad + c0 + c_l) * 8]) =
        *reinterpret_cast<const short8*>(u);
  }
}

// ---------------- k1b gemm (round-5 proven): BM=256, BN=64, BK=64 ----------------
__global__ __launch_bounds__(256, 3) void gemm_k1b(
    const unsigned short* __restrict__ A, int lda,
    const float* __restrict__ B0, const float* __restrict__ B1,
    float* __restrict__ P1, int nz)
{
  __shared__ unsigned short As[256*64];
  __shared__ unsigned short Bs[64*80];

  const int tid  = threadIdx.x;
  const int lane = tid & 63, wid = tid >> 6;
  const int lr = lane & 15, lg = lane >> 4;

  int id = blockIdx.x;          // 2 mb * 5 cb * nz
  int mb = id & 1; id >>= 1;
  int cb = id % 5, z = id / 5;
  const int m0 = mb*256, c0 = cb*64;
  const int ksplit = 6*D_;

  const int r8 = lane >> 3, sl = lane & 7;
  const int c_l = tid & 63, ob = tid >> 6;
  const int gcol = c0 + c_l;
  const bool cok = (gcol < D_);

  f32x4 acc[4][4];
  #pragma unroll
  for (int a = 0; a < 4; ++a)
    #pragma unroll
    for (int b = 0; b < 4; ++b) acc[a][b] = (f32x4){0.f,0.f,0.f,0.f};

  for (int t = z; t < 33; t += nz) {
    const int kt = t * 64;
    __syncthreads();

    #pragma unroll
    for (int i = 0; i < 8; ++i) {
      int row_l = wid*64 + i*8 + r8;
      int sslot = sl ^ (row_l & 7);
      gload_lds16(A + (size_t)(m0 + row_l)*lda + kt + sslot*8, &As[(wid*64 + i*8)*64]);
    }

    #pragma unroll
    for (int it = 0; it < 2; ++it) {
      int o  = ob + it*4;
      int kb = kt + o*8;
      unsigned short u[8];
      #pragma unroll
      for (int j = 0; j < 8; ++j) {
        int k = kb + j;
        float v = 0.f;
        if (cok && k < KTOT)
          v = (k < ksplit) ? B0[(size_t)k*D_ + gcol]
                           : B1[(size_t)(k - ksplit)*D_ + gcol];
        u[j] = f2bf(v);
      }
      *reinterpret_cast<short8*>(&Bs[c_l*80 + ((o ^ (c_l & 7)) << 3)]) =
          *reinterpret_cast<const short8*>(u);
    }

    __syncthreads();

    #pragma unroll
    for (int kk = 0; kk < 2; ++kk) {
      const int q = kk*4 + lg;
      short8 bfr[4];
      #pragma unroll
      for (int b = 0; b < 4; ++b) {
        int col = b*16 + lr;
        bfr[b] = *reinterpret_cast<const short8*>(&Bs[col*80 + ((q ^ (col & 7)) << 3)]);
      }
      #pragma unroll
      for (int a = 0; a < 4; ++a) {
        int row = wid*64 + a*16 + lr;
        short8 af = *reinterpret_cast<const short8*>(&As[row*64 + ((q ^ (row & 7)) << 3)]);
        #pragma unroll
        for (int b = 0; b < 4; ++b)
          acc[a][b] = __builtin_amdgcn_mfma_f32_16x16x32_bf16(af, bfr[b], acc[a][b], 0, 0, 0);
      }
    }
  }

  float* o = P1 + (size_t)z * (size_t)B_ * PLD;
  #pragma unroll
  for (int a = 0; a < 4; ++a) {
    int row = m0 + wid*64 + a*16 + lg*4;
    #pragma unroll
    for (int b = 0; b < 4; ++b) {
      int col = c0 + b*16 + lr;
      if (col < D_) {
        #pragma unroll
        for (int i = 0; i < 4; ++i)
          o[(size_t)(row + i)*PLD + col] = acc[a][b][i];
      }
    }
  }
}

// ---------------- K1c: reduce z-partials, leaky, emit bf16 X0H [512][320] ----------------
__global__ __launch_bounds__(256) void k1c_reduce(
    const float* __restrict__ part, int nz, unsigned short* __restrict__ X0Hbf)
{
  int idx = blockIdx.x*256 + threadIdx.x;
  if (idx >= B_*XLD) return;
  int m = idx / XLD, c = idx % XLD;
  float v = 0.f;
  if (c < D_) {
    for (int zz = 0; zz < nz; ++zz) v += part[(size_t)zz*B_*PLD + (size_t)m*PLD + c];
    v = (v >= 0.f) ? v : 0.1f*v;
  }
  X0Hbf[idx] = f2bf(v);
}

// ---------------- gemm12: heads, two-pass recompute; 4 tiles/block ----------------
// BM=128 per block (mb=0..3); grid = 4*GRP12 = 1176 = 8*147, bijective XCD swizzle.
// A-fragments loaded ONCE per block; per tile: 10 DMA + 5 counted-vmcnt stages.
// Max per-wave vmem queue = 10 + 44 = 54 < 63 (vmcnt counter range) — do NOT deepen.
// MODE 0: per-row (max,sumexp) -> part.
// MODE 1: out = acc + bias - lse[row], stores staged through per-wave LDS so every
//         global_store covers one row x 256B contiguous. Epilogue vmem count = 44.
template<int MODE>
__global__ __launch_bounds__(256, 3) void gemm12(
    const unsigned short* __restrict__ X0H,
    const unsigned short* __restrict__ Wttg, const unsigned short* __restrict__ Wtts,
    const float* __restrict__ bg, const float* __restrict__ bs,
    float* __restrict__ out, float2* __restrict__ Pg, float2* __restrict__ Ps,
    const float* __restrict__ lse)
{
  __shared__ unsigned short Bs[5][4096];   // 5 stages x 8 KB
  __shared__ float eplds[2080];            // 4 waves x [8][65] fp32 (8.3 KB)

  int bid = blockIdx.x;                    // 1176 = 8*147
  int id = (bid & 7) * 147 + (bid >> 3);
  const int mb = id & 3;
  const int g  = id >> 2;                  // 0..293
  const int m0 = mb * 128;

  const int tid = threadIdx.x;
  const int lane = tid & 63, w = tid >> 6;
  const int lr = lane & 15, lg = lane >> 4;

  // ---- A fragments, once per block ----
  short8 af[2][10];
  #pragma unroll
  for (int a = 0; a < 2; ++a) {
    const unsigned short* Ar = X0H + (size_t)(m0 + w*32 + a*16 + lr)*XLD + lg*8;
    #pragma unroll
    for (int ks = 0; ks < 10; ++ks)
      af[a][ks] = *reinterpret_cast<const short8*>(Ar + ks*32);
  }
  __builtin_amdgcn_sched_barrier(0);

  auto dma_tile = [&](int tt) {
    const bool hg = (tt < NCBG);
    const unsigned short* Wtt = hg ? Wttg : Wtts;
    const size_t cp = hg ? CPADG : CPADS;
    const int C = hg ? NG_ : NS_;
    const int cb = hg ? tt : tt - NCBG;
    const int c0c = min(cb*64, C - 64);
    #pragma unroll
    for (int j = 0; j < 5; ++j) {
      #pragma unroll
      for (int i2 = 0; i2 < 2; ++i2) {
        int o = w*2 + i2;
        gload_lds16(Wtt + ((size_t)(j*8 + o)*cp + (size_t)c0c + lane)*8, &Bs[j][o*512]);
      }
    }
  };

  dma_tile(g);
  __builtin_amdgcn_sched_barrier(0);

  f32x4 acc[2][4];

#define MF12(j) do {                                                           \
    _Pragma("unroll")                                                          \
    for (int kk = 0; kk < 2; ++kk) {                                           \
      short8 bfr[4];                                                           \
      _Pragma("unroll")                                                        \
      for (int b = 0; b < 4; ++b)                                              \
        bfr[b] = *reinterpret_cast<const short8*>(                             \
            &Bs[j][(kk*4 + lg)*512 + (b*16 + lr)*8]);                          \
      _Pragma("unroll")                                                        \
      for (int a = 0; a < 2; ++a)                                              \
        _Pragma("unroll")                                                      \
        for (int b = 0; b < 4; ++b)                                            \
          acc[a][b] = __builtin_amdgcn_mfma_f32_16x16x32_bf16(                 \
              af[a][(j)*2 + kk], bfr[b], acc[a][b], 0, 0, 0);                  \
    }                                                                          \
  } while (0)

#define ST12(j, NSTR) do {                                                     \
    asm volatile("s_waitcnt vmcnt(" NSTR ")" ::: "memory");                    \
    __builtin_amdgcn_s_barrier();                                              \
    __builtin_amdgcn_sched_barrier(0);                                         \
    MF12(j);                                                                   \
  } while (0)

  for (int tl = 0; tl < 4; ++tl) {
    const int tt = g + tl*GRP12;
    if (tt >= NTILE) break;

    #pragma unroll
    for (int a = 0; a < 2; ++a)
      #pragma unroll
      for (int b = 0; b < 4; ++b) acc[a][b] = (f32x4){0.f,0.f,0.f,0.f};

    if (tl == 0) {
      ST12(0, "8"); ST12(1, "6"); ST12(2, "4"); ST12(3, "2"); ST12(4, "0");
    } else if (MODE == 0) {
      // queue: [D_cur:10][E_prev:12];  count = 12 + 8 - 2j
      ST12(0, "20"); ST12(1, "18"); ST12(2, "16"); ST12(3, "14"); ST12(4, "12");
    } else {
      // queue: [D_cur:10][E_prev:44];  count = 44 + 8 - 2j
      ST12(0, "52"); ST12(1, "50"); ST12(2, "48"); ST12(3, "46"); ST12(4, "44");
    }

    // Bs free after all waves' stage-4 ds_reads complete
    asm volatile("s_waitcnt lgkmcnt(0)" ::: "memory");
    __builtin_amdgcn_s_barrier();
    __builtin_amdgcn_sched_barrier(0);

    const int tn = tt + GRP12;
    if (tl < 3 && tn < NTILE) dma_tile(tn);
    __builtin_amdgcn_sched_barrier(0);

    // ---- epilogue (clamped window; stable op counts) ----
    {
      const bool hg = (tt < NCBG);
      const int C = hg ? NG_ : NS_;
      const int cb = hg ? tt : tt - NCBG;
      const int c0o = cb*64;
      const int c0c = min(c0o, C - 64);
      const float* bia = hg ? bg : bs;

      float bv[4];
      #pragma unroll
      for (int b = 0; b < 4; ++b) bv[b] = bia[c0c + b*16 + lr];   // 4 loads

      if constexpr (MODE == 0) {
        float2* part = hg ? Pg : Ps;
        #pragma unroll
        for (int a = 0; a < 2; ++a) {
          #pragma unroll
          for (int i = 0; i < 4; ++i) {
            int row = m0 + w*32 + a*16 + lg*4 + i;
            float v[4], mx = -3.0e38f;
            #pragma unroll
            for (int b = 0; b < 4; ++b) {
              v[b] = acc[a][b][i] + bv[b];
              if (c0c + b*16 + lr < c0o) v[b] = -3.0e38f;   // mask duplicate cols
              mx = fmaxf(mx, v[b]);
            }
            #pragma unroll
            for (int off = 1; off < 16; off <<= 1) mx = fmaxf(mx, __shfl_xor(mx, off));
            float s = 0.f;
            #pragma unroll
            for (int b = 0; b < 4; ++b) s += __expf(v[b] - mx);
            #pragma unroll
            for (int off = 1; off < 16; off <<= 1) s += __shfl_xor(s, off);
            if (lr == 0) part[(size_t)cb*512 + row] = make_float2(mx, s);  // 8 stores
          }
        }
      } else {
        float* outp = hg ? out : out + (size_t)B_*NG_;
        const float* lp = lse + (hg ? 0 : 512);
        float* ep = &eplds[w * 520];          // per-wave [8][65]
        #pragma unroll
        for (int a = 0; a < 2; ++a) {
          #pragma unroll
          for (int ip = 0; ip < 2; ++ip) {
            // WAR fence: previous round's reads done before overwriting (wave-local)
            asm volatile("s_waitcnt lgkmcnt(0)" ::: "memory");
            __builtin_amdgcn_sched_barrier(0);
            #pragma unroll
            for (int d = 0; d < 2; ++d) {
              int grow = m0 + w*32 + a*16 + lg*4 + 2*ip + d;
              float L = lp[grow];                                  // 8 lse loads total
              #pragma unroll
              for (int b = 0; b < 4; ++b)
                ep[(2*lg + d)*65 + b*16 + lr] = acc[a][b][2*ip + d] + bv[b] - L;
            }
            asm volatile("s_waitcnt lgkmcnt(0)" ::: "memory");
            __builtin_amdgcn_sched_barrier(0);
            #pragma unroll
            for (int rloc = 0; rloc < 8; ++rloc) {
              float v = ep[rloc*65 + lane];
              int grow = m0 + w*32 + a*16 + 4*(rloc >> 1) + 2*ip + (rloc & 1);
              outp[(size_t)grow*C + c0c + lane] = v;               // 32 stores total
            }
          }
        }
      }
    }
    __builtin_amdgcn_sched_barrier(0);
  }
#undef MF12
#undef ST12
}

// ---------------- k5b: combine tile-major (m,s) partials -> lse[1024] ----------------
__global__ __launch_bounds__(256) void k5b(
    const float2* __restrict__ Pg, const float2* __restrict__ Ps,
    float* __restrict__ lse)
{
  const int blk = blockIdx.x;            // 0..127
  const bool hg = (blk < 64);
  const float2* p = hg ? Pg : Ps;
  const int n = hg ? NCBG : NCBS;
  const int r0 = (hg ? blk : blk - 64) * 8;
  const int tid = threadIdx.x;
  const int rr = tid & 7;
  const int row = r0 + rr;

  float m = -3.0e38f, s = 0.f;
  for (int t = tid >> 3; t < n; t += 32) {
    float2 v = p[(size_t)t*512 + row];
    float mn = fmaxf(m, v.x);
    s = s*__expf(m - mn) + v.y*__expf(v.x - mn);
    m = mn;
  }
  #pragma unroll
  for (int off = 8; off < 64; off <<= 1) {
    float m2 = __shfl_xor(m, off), s2 = __shfl_xor(s, off);
    float mn = fmaxf(m, m2);
    s = s*__expf(m - mn) + s2*__expf(m2 - mn);
    m = mn;
  }
  __shared__ float ms[4][8], ss[4][8];
  const int wv = tid >> 6;
  if ((tid & 63) < 8) { ms[wv][tid & 7] = m; ss[wv][tid & 7] = s; }
  __syncthreads();
  if (tid < 8) {
    float M = ms[0][tid], S = ss[0][tid];
    #pragma unroll
    for (int ww = 1; ww < 4; ++ww) {
      float mn = fmaxf(M, ms[ww][tid]);
      S = S*__expf(M - mn) + ss[ww][tid]*__expf(ms[ww][tid] - mn);
      M = mn;
    }
    lse[(hg ? 0 : 512) + r0 + tid] = M + __logf(S);
  }
}

// =====================================================================
extern "C" void kernel_launch(void* const* d_in, const int* in_sizes, int n_in,
                              void* d_out, int out_size, void* d_ws, size_t ws_size,
                              hipStream_t stream)
{
  const float* x    = (const float*)d_in[0];
  const int*   ei   = (const int*)  d_in[1];
  const int*   et   = (const int*)  d_in[2];
  const float* Wrel = (const float*)d_in[3];
  const float* W0   = (const float*)d_in[4];
  const float* Wg   = (const float*)d_in[5];
  const float* bg   = (const float*)d_in[6];
  const float* Ws   = (const float*)d_in[7];
  const float* bs   = (const float*)d_in[8];
  float* out = (float*)d_out;

  // ws layout (bytes): Ybf | X0H | P1 | Pg | Ps | LSE | Wttg | Wtts (~60.3 MB)
  char* p = (char*)d_ws;
  unsigned short* Ybf = (unsigned short*)p;  p += (size_t)B_*YLD*2;
  unsigned short* X0H = (unsigned short*)p;  p += (size_t)B_*XLD*2;
  float*  P1  = (float*)p;                   p += (size_t)8*B_*PLD*4;
  float2* Pg  = (float2*)p;                  p += (size_t)NCBG*512*8;
  float2* Ps  = (float2*)p;                  p += (size_t)NCBS*512*8;
  float*  LSE = (float*)p;                   p += 4096;
  unsigned short* Wttg = (unsigned short*)p; p += (size_t)40*CPADG*16;
  unsigned short* Wtts = (unsigned short*)p;

  // W pre-transpose, both heads, wide-chunk reads (low VGPR, one launch)
  wtrans3<<<980 + 490, 256, 0, stream>>>(Wg, Wttg, Ws, Wtts);

  k1a_coef_y<<<dim3(B_, 2), 256, 0, stream>>>(x, ei, et, Ybf);

  // k1b: P1[z] = Y @ [Wrel;W0] partials (z-split over 33 K-tiles)
  gemm_k1b<<<2*5*8, 256, 0, stream>>>(Ybf, YLD, Wrel, W0, P1, 8);
  k1c_reduce<<<(B_*XLD + 255)/256, 256, 0, stream>>>(P1, 8, X0H);

  // pass1: per-tile row stats -> Pg/Ps (no logits write)
  gemm12<0><<<4*GRP12, 256, 0, stream>>>(X0H, Wttg, Wtts, bg, bs,
                                         nullptr, Pg, Ps, nullptr);
  k5b<<<128, 256, 0, stream>>>(Pg, Ps, LSE);

  // pass2: recompute logits, write out = acc + bias - lse
  gemm12<1><<<4*GRP12, 256, 0, stream>>>(X0H, Wttg, Wtts, bg, bs,
                                         out, nullptr, nullptr, LSE);
}